// Round 1
// baseline (1042.975 us; speedup 1.0000x reference)
//
#include <hip/hip_runtime.h>

// Window attention: B=8, C=512 (8 heads x 64 hd), H=W=128, ws=8.
// One block per window (16384 blocks, 256 threads = 4 waves).
// LDS buffers d-major [d][token], stride 65 (=> <=2-way bank conflicts).
// S = Q*K^T and O = P*V via mfma_f32_16x16x32_bf16 (fp32 accumulate).

typedef __attribute__((ext_vector_type(8))) short short8;
typedef __attribute__((ext_vector_type(4))) float f32x4;

__device__ __forceinline__ short f2bf(float x) {
    unsigned u = __builtin_bit_cast(unsigned, x);
    u += 0x7fffu + ((u >> 16) & 1u);   // RTNE
    return (short)(u >> 16);
}

__global__ __launch_bounds__(256) void win_attn(
    const float* __restrict__ qg, const float* __restrict__ kg,
    const float* __restrict__ vg, float* __restrict__ og)
{
    __shared__ float sQ[64 * 65];  // Q (d-major) -> later P (row-major [row][k])
    __shared__ float sK[64 * 65];  // K (d-major) -> later O (d-major)
    __shared__ float sV[64 * 65];  // V (d-major)

    const int tid  = threadIdx.x;
    const int lane = tid & 63;
    const int w    = tid >> 6;     // wave id: query-row strip [16w, 16w+16)
    const int l16  = lane & 15;
    const int quad = lane >> 4;

    const int wid = blockIdx.x;
    const int wx = wid & 15;
    const int wy = (wid >> 4) & 15;
    // wid>>8 == b*8 + h ; channel base = (b*8+h)*64
    const long base = (long)(wid >> 8) * 64 * 16384 + (long)(wy * 8) * 128 + wx * 8;

    // ---- stage Q,K,V global->LDS (float4 loads, 32B segments per (d,row)) ----
    #pragma unroll
    for (int i = 0; i < 4; ++i) {
        int f4 = i * 256 + tid;            // float4 index, 1024 per matrix
        int d  = f4 >> 4;
        int t0 = (f4 & 15) << 2;           // token 0..60 step 4 (same spatial row)
        long g = base + (long)d * 16384 + (t0 >> 3) * 128 + (t0 & 7);
        float4 a = *(const float4*)(qg + g);
        float4 bq = *(const float4*)(kg + g);
        float4 c = *(const float4*)(vg + g);
        int l = d * 65 + t0;
        sQ[l + 0] = a.x * 0.125f; sQ[l + 1] = a.y * 0.125f;
        sQ[l + 2] = a.z * 0.125f; sQ[l + 3] = a.w * 0.125f;
        sK[l + 0] = bq.x; sK[l + 1] = bq.y; sK[l + 2] = bq.z; sK[l + 3] = bq.w;
        sV[l + 0] = c.x;  sV[l + 1] = c.y;  sV[l + 2] = c.z;  sV[l + 3] = c.w;
    }
    __syncthreads();

    // ---- S = Q*K^T : A[m=16w+l16][k=d], B[n=l16+16T][k=d] -------------------
    short8 aq[2];
    #pragma unroll
    for (int kc = 0; kc < 2; ++kc)
        #pragma unroll
        for (int j = 0; j < 8; ++j)
            aq[kc][j] = f2bf(sQ[(kc * 32 + quad * 8 + j) * 65 + w * 16 + l16]);

    f32x4 accS[4];
    #pragma unroll
    for (int T = 0; T < 4; ++T) accS[T] = (f32x4){0.f, 0.f, 0.f, 0.f};

    #pragma unroll
    for (int T = 0; T < 4; ++T)
        #pragma unroll
        for (int kc = 0; kc < 2; ++kc) {
            short8 bk;
            #pragma unroll
            for (int j = 0; j < 8; ++j)
                bk[j] = f2bf(sK[(kc * 32 + quad * 8 + j) * 65 + T * 16 + l16]);
            accS[T] = __builtin_amdgcn_mfma_f32_16x16x32_bf16(aq[kc], bk, accS[T], 0, 0, 0);
        }

    // ---- softmax over each row (rows live in 16-lane groups, shfl reduce) ---
    float p[4][4];      // [T][reg]
    float invl[4];
    #pragma unroll
    for (int r = 0; r < 4; ++r) {
        float m = fmaxf(fmaxf(accS[0][r], accS[1][r]), fmaxf(accS[2][r], accS[3][r]));
        #pragma unroll
        for (int off = 1; off <= 8; off <<= 1)
            m = fmaxf(m, __shfl_xor(m, off, 64));
        float s = 0.f;
        #pragma unroll
        for (int T = 0; T < 4; ++T) { p[T][r] = __expf(accS[T][r] - m); s += p[T][r]; }
        #pragma unroll
        for (int off = 1; off <= 8; off <<= 1)
            s += __shfl_xor(s, off, 64);
        invl[r] = 1.0f / s;
    }

    __syncthreads();   // all waves done reading sQ (and sK) in S-phase

    // ---- write P (unnormalized) over sQ as [row][k] -------------------------
    #pragma unroll
    for (int T = 0; T < 4; ++T)
        #pragma unroll
        for (int r = 0; r < 4; ++r)
            sQ[(w * 16 + quad * 4 + r) * 65 + T * 16 + l16] = p[T][r];
    // each wave reads back only its own strip -> no barrier needed (lgkmcnt ordering)

    // ---- O = P*V : A[m=16w+l16][k=tok], B[n=d=16T+l16][k=tok] ---------------
    f32x4 accO[4];
    #pragma unroll
    for (int T = 0; T < 4; ++T) accO[T] = (f32x4){0.f, 0.f, 0.f, 0.f};

    #pragma unroll
    for (int kc = 0; kc < 2; ++kc) {
        short8 ap;
        #pragma unroll
        for (int j = 0; j < 8; ++j)
            ap[j] = f2bf(sQ[(w * 16 + l16) * 65 + kc * 32 + quad * 8 + j]);
        #pragma unroll
        for (int T = 0; T < 4; ++T) {
            short8 bv;
            #pragma unroll
            for (int j = 0; j < 8; ++j)
                bv[j] = f2bf(sV[(T * 16 + l16) * 65 + kc * 32 + quad * 8 + j]);
            accO[T] = __builtin_amdgcn_mfma_f32_16x16x32_bf16(ap, bv, accO[T], 0, 0, 0);
        }
    }

    // ---- O -> sK (d-major) for coalesced store ------------------------------
    #pragma unroll
    for (int T = 0; T < 4; ++T)
        #pragma unroll
        for (int r = 0; r < 4; ++r)
            sK[(T * 16 + l16) * 65 + w * 16 + quad * 4 + r] = accO[T][r] * invl[r];

    __syncthreads();

    // ---- coalesced copy-out -------------------------------------------------
    #pragma unroll
    for (int i = 0; i < 4; ++i) {
        int f4 = i * 256 + tid;
        int d  = f4 >> 4;
        int t0 = (f4 & 15) << 2;
        long g = base + (long)d * 16384 + (t0 >> 3) * 128 + (t0 & 7);
        int l = d * 65 + t0;
        float4 o;
        o.x = sK[l + 0]; o.y = sK[l + 1]; o.z = sK[l + 2]; o.w = sK[l + 3];
        *(float4*)(og + g) = o;
    }
}

extern "C" void kernel_launch(void* const* d_in, const int* in_sizes, int n_in,
                              void* d_out, int out_size, void* d_ws, size_t ws_size,
                              hipStream_t stream) {
    (void)in_sizes; (void)n_in; (void)d_ws; (void)ws_size; (void)out_size;
    const float* q = (const float*)d_in[0];
    const float* k = (const float*)d_in[1];
    const float* v = (const float*)d_in[2];
    float* out = (float*)d_out;
    win_attn<<<dim3(16384), dim3(256), 0, stream>>>(q, k, v, out);
}